// Round 1
// baseline (473.657 us; speedup 1.0000x reference)
//
#include <hip/hip_runtime.h>
#include <math.h>

#define N_SP 3136
#define BN_EPS 1e-5f

// ws layout (float elements)
#define QK_SZ   (16*2*384*N_SP)          // 38,535,168
#define KVP_OFF (QK_SZ)
#define KVP_SZ  (16*6*7*64*64)           // 2,752,512
#define KMP_OFF (KVP_OFF + KVP_SZ)
#define KMP_SZ  (16*6*7*64)              // 43,008
#define KV_OFF  (KMP_OFF + KMP_SZ)
#define KV_SZ   (16*6*64*64)             // 393,216
#define KM_OFF  (KV_OFF + KV_SZ)

// ---------------- K1: qk GEMM (per b,g: C[384x3136] = W[384x192] * X[192x3136]) + BN + elu+1
__global__ __launch_bounds__(256) void k1_qk_gemm(
    const float* __restrict__ x, const float* __restrict__ qk_w,
    const float* __restrict__ gamma, const float* __restrict__ beta,
    const float* __restrict__ mean, const float* __restrict__ var,
    float* __restrict__ qk_out)
{
    __shared__ float As[32][68];   // [k][o]
    __shared__ float Bs[32][68];   // [k][n]
    const int bx = blockIdx.x;          // n tile (49)
    const int by = blockIdx.y;          // o tile (6)
    const int bz = blockIdx.z;          // b*2+g (32)
    const int b = bz >> 1, g = bz & 1;
    const int t = threadIdx.x;
    const int tx = t & 15, ty = t >> 4;
    const float* wg = qk_w + g*384*192;
    const float* xg = x + (b*384 + g*192)*N_SP;
    const int n0 = bx*64, o0 = by*64;

    float acc[4][4] = {};
    for (int kt = 0; kt < 6; ++kt) {
        #pragma unroll
        for (int l = 0; l < 2; ++l) {
            int idx = t + l*256;
            int r = idx >> 3, c = idx & 7;
            float4 a4 = *(const float4*)&wg[(o0 + r)*192 + kt*32 + c*4];
            As[c*4+0][r] = a4.x; As[c*4+1][r] = a4.y;
            As[c*4+2][r] = a4.z; As[c*4+3][r] = a4.w;
        }
        #pragma unroll
        for (int l = 0; l < 2; ++l) {
            int idx = t + l*256;
            int r = idx >> 4, c = idx & 15;
            *(float4*)&Bs[r][c*4] = *(const float4*)&xg[(kt*32 + r)*N_SP + n0 + c*4];
        }
        __syncthreads();
        #pragma unroll 8
        for (int k = 0; k < 32; ++k) {
            float4 a  = *(const float4*)&As[k][ty*4];
            float4 bv = *(const float4*)&Bs[k][tx*4];
            float av[4] = {a.x, a.y, a.z, a.w};
            float bb[4] = {bv.x, bv.y, bv.z, bv.w};
            #pragma unroll
            for (int i = 0; i < 4; ++i)
                #pragma unroll
                for (int j = 0; j < 4; ++j)
                    acc[i][j] += av[i] * bb[j];
        }
        __syncthreads();
    }
    const int out_base = ((b*2+g)*384)*N_SP;
    #pragma unroll
    for (int i = 0; i < 4; ++i) {
        int o = o0 + ty*4 + i;
        int ch = g*384 + o;
        float sc = gamma[ch] / sqrtf(var[ch] + BN_EPS);
        float sh = beta[ch] - mean[ch]*sc;
        float4 r;
        float* pr = (float*)&r;
        #pragma unroll
        for (int j = 0; j < 4; ++j) {
            float v = acc[i][j]*sc + sh;
            pr[j] = v > 0.f ? v + 1.f : expf(v);   // elu(v)+1
        }
        *(float4*)&qk_out[out_base + o*N_SP + n0 + tx*4] = r;
    }
}

// ---------------- K2: per (b,h,chunk): partial kv[d][e] = sum_n k[d,n]*v[e,n]; partial km[d]
__global__ __launch_bounds__(256) void k2_kv(
    const float* __restrict__ x, const float* __restrict__ qk,
    float* __restrict__ kv_part, float* __restrict__ km_part)
{
    __shared__ float ks[64][68];  // [n][d]
    __shared__ float vs[64][68];  // [n][e]
    const int chunk = blockIdx.x;      // 7
    const int h = blockIdx.y, b = blockIdx.z;
    const int t = threadIdx.x, tx = t & 15, ty = t >> 4;
    const float* kp = qk + ((b*2+1)*384 + h*64)*N_SP;
    const float* vp = x  + (b*384 + h*64)*N_SP;
    float acc[4][4] = {};
    float kmacc[4] = {};
    for (int sub = 0; sub < 7; ++sub) {
        int n0 = chunk*448 + sub*64;
        #pragma unroll
        for (int l = 0; l < 4; ++l) {
            int idx = t + l*256;
            int d = idx >> 4, c = idx & 15;
            float4 v4 = *(const float4*)&kp[d*N_SP + n0 + c*4];
            ks[c*4+0][d] = v4.x; ks[c*4+1][d] = v4.y;
            ks[c*4+2][d] = v4.z; ks[c*4+3][d] = v4.w;
        }
        #pragma unroll
        for (int l = 0; l < 4; ++l) {
            int idx = t + l*256;
            int e = idx >> 4, c = idx & 15;
            float4 v4 = *(const float4*)&vp[e*N_SP + n0 + c*4];
            vs[c*4+0][e] = v4.x; vs[c*4+1][e] = v4.y;
            vs[c*4+2][e] = v4.z; vs[c*4+3][e] = v4.w;
        }
        __syncthreads();
        #pragma unroll 8
        for (int n = 0; n < 64; ++n) {
            float4 kd = *(const float4*)&ks[n][ty*4];
            float4 ve = *(const float4*)&vs[n][tx*4];
            float kk[4] = {kd.x,kd.y,kd.z,kd.w}, vv[4] = {ve.x,ve.y,ve.z,ve.w};
            #pragma unroll
            for (int i = 0; i < 4; ++i) {
                kmacc[i] += kk[i];
                #pragma unroll
                for (int j = 0; j < 4; ++j) acc[i][j] += kk[i]*vv[j];
            }
        }
        __syncthreads();
    }
    const int base = ((b*6+h)*7 + chunk)*4096;
    #pragma unroll
    for (int i = 0; i < 4; ++i) {
        float4 r = make_float4(acc[i][0], acc[i][1], acc[i][2], acc[i][3]);
        *(float4*)&kv_part[base + (ty*4+i)*64 + tx*4] = r;
    }
    if (tx == 0) {
        const int kb = ((b*6+h)*7 + chunk)*64;
        #pragma unroll
        for (int i = 0; i < 4; ++i) km_part[kb + ty*4+i] = kmacc[i];
    }
}

// ---------------- K2b: reduce partials; kv *= 1/N (= s^2), km = mean
__global__ __launch_bounds__(256) void k2b_reduce(
    const float* __restrict__ kv_part, const float* __restrict__ km_part,
    float* __restrict__ kv, float* __restrict__ km)
{
    int idx = blockIdx.x*256 + threadIdx.x;
    const float inv_n = 1.0f / (float)N_SP;
    if (idx < 16*6*64*64) {
        int bh = idx >> 12, de = idx & 4095;
        float s = 0.f;
        #pragma unroll
        for (int c = 0; c < 7; ++c) s += kv_part[(bh*7+c)*4096 + de];
        kv[idx] = s * inv_n;
    }
    if (idx < 16*6*64) {
        int bh = idx >> 6, d = idx & 63;
        float s = 0.f;
        #pragma unroll
        for (int c = 0; c < 7; ++c) s += km_part[(bh*7+c)*64 + d];
        km[idx] = s * inv_n;
    }
}

// ---------------- K3: out[b, h*64+e, n] = (sum_d q[d,n]*kv[d,e]) / (sum_d q[d,n]*km[d] + 1e-6)
__global__ __launch_bounds__(256) void k3_attn(
    const float* __restrict__ qk, const float* __restrict__ kv,
    const float* __restrict__ km, float* __restrict__ out)
{
    __shared__ float qs[64][68];   // [d][n]
    __shared__ float kvs[64][68];  // [d][e]
    __shared__ float kms[64];
    const int bx = blockIdx.x;    // 49 n tiles
    const int h = blockIdx.y, b = blockIdx.z;
    const int t = threadIdx.x, tx = t & 15, ty = t >> 4;
    const int n0 = bx*64;
    const float* qp  = qk + ((b*2+0)*384 + h*64)*N_SP;
    const float* kvp = kv + (b*6+h)*4096;
    #pragma unroll
    for (int l = 0; l < 4; ++l) {
        int idx = t + l*256;
        int d = idx >> 4, c = idx & 15;
        *(float4*)&qs[d][c*4] = *(const float4*)&qp[d*N_SP + n0 + c*4];
    }
    #pragma unroll
    for (int l = 0; l < 4; ++l) {
        int idx = t + l*256;
        int d = idx >> 4, c = idx & 15;
        *(float4*)&kvs[d][c*4] = *(const float4*)&kvp[d*64 + c*4];
    }
    if (t < 64) kms[t] = km[(b*6+h)*64 + t];
    __syncthreads();
    float acc[4][4] = {};
    float den[4] = {};
    #pragma unroll 8
    for (int d = 0; d < 64; ++d) {
        float4 qn = *(const float4*)&qs[d][ty*4];
        float4 ke = *(const float4*)&kvs[d][tx*4];
        float qq[4] = {qn.x,qn.y,qn.z,qn.w}, kk[4] = {ke.x,ke.y,ke.z,ke.w};
        float kmd = kms[d];
        #pragma unroll
        for (int i = 0; i < 4; ++i) {
            den[i] += qq[i]*kmd;
            #pragma unroll
            for (int j = 0; j < 4; ++j) acc[i][j] += qq[i]*kk[j];
        }
    }
    #pragma unroll
    for (int j = 0; j < 4; ++j) {
        int c = h*64 + tx*4 + j;
        float4 r;
        r.x = acc[0][j] / (den[0] + 1e-6f);
        r.y = acc[1][j] / (den[1] + 1e-6f);
        r.z = acc[2][j] / (den[2] + 1e-6f);
        r.w = acc[3][j] / (den[3] + 1e-6f);
        *(float4*)&out[(b*384 + c)*N_SP + n0 + ty*4] = r;
    }
}

// ---------------- K4: depthwise 3x3 conv + BN, += into out
__global__ __launch_bounds__(256) void k4_pe(
    const float* __restrict__ x, const float* __restrict__ pw,
    const float* __restrict__ gamma, const float* __restrict__ beta,
    const float* __restrict__ mean, const float* __restrict__ var,
    float* __restrict__ out)
{
    int idx = blockIdx.x*256 + threadIdx.x;
    if (idx >= 16*384*N_SP) return;
    int n  = idx % N_SP;
    int bc = idx / N_SP;
    int c  = bc % 384;
    int y = n / 56, xw = n % 56;
    const float* xp = x + bc*N_SP;
    float s = 0.f;
    #pragma unroll
    for (int dy = -1; dy <= 1; ++dy) {
        int yy = y + dy;
        if (yy < 0 || yy >= 56) continue;
        #pragma unroll
        for (int dx = -1; dx <= 1; ++dx) {
            int xx = xw + dx;
            if (xx < 0 || xx >= 56) continue;
            s += xp[yy*56 + xx] * pw[c*9 + (dy+1)*3 + (dx+1)];
        }
    }
    float sc = gamma[c] / sqrtf(var[c] + BN_EPS);
    float sh = beta[c] - mean[c]*sc;
    out[idx] += s*sc + sh;
}

extern "C" void kernel_launch(void* const* d_in, const int* in_sizes, int n_in,
                              void* d_out, int out_size, void* d_ws, size_t ws_size,
                              hipStream_t stream)
{
    const float* x        = (const float*)d_in[0];
    const float* qk_w     = (const float*)d_in[1];
    const float* qk_gamma = (const float*)d_in[2];
    const float* qk_beta  = (const float*)d_in[3];
    const float* qk_mean  = (const float*)d_in[4];
    const float* qk_var   = (const float*)d_in[5];
    const float* pe_w     = (const float*)d_in[6];
    const float* pe_gamma = (const float*)d_in[7];
    const float* pe_beta  = (const float*)d_in[8];
    const float* pe_mean  = (const float*)d_in[9];
    const float* pe_var   = (const float*)d_in[10];
    float* out = (float*)d_out;

    float* ws      = (float*)d_ws;
    float* qk      = ws;            // QK_SZ
    float* kv_part = ws + KVP_OFF;
    float* km_part = ws + KMP_OFF;
    float* kv      = ws + KV_OFF;
    float* km      = ws + KM_OFF;

    dim3 g1(49, 6, 32);
    hipLaunchKernelGGL(k1_qk_gemm, g1, dim3(256), 0, stream,
                       x, qk_w, qk_gamma, qk_beta, qk_mean, qk_var, qk);
    dim3 g2(7, 6, 16);
    hipLaunchKernelGGL(k2_kv, g2, dim3(256), 0, stream, x, qk, kv_part, km_part);
    hipLaunchKernelGGL(k2b_reduce, dim3(1536), dim3(256), 0, stream,
                       kv_part, km_part, kv, km);
    dim3 g3(49, 6, 16);
    hipLaunchKernelGGL(k3_attn, g3, dim3(256), 0, stream, qk, kv, km, out);
    hipLaunchKernelGGL(k4_pe, dim3(75264), dim3(256), 0, stream,
                       x, pe_w, pe_gamma, pe_beta, pe_mean, pe_var, out);
}

// Round 2
// 321.158 us; speedup vs baseline: 1.4748x; 1.4748x over previous
//
#include <hip/hip_runtime.h>
#include <math.h>

#define N_SP 3136
#define BN_EPS 1e-5f

typedef __attribute__((ext_vector_type(8))) short short8;
typedef __attribute__((ext_vector_type(4))) float f32x4;

// ws layout (float elements)
#define QK_SZ   (16*2*384*N_SP)          // 38,535,168
#define KVP_OFF (QK_SZ)
#define KVP_SZ  (16*6*7*64*64)           // 2,752,512
#define KMP_OFF (KVP_OFF + KVP_SZ)
#define KMP_SZ  (16*6*7*64)              // 43,008
#define KV_OFF  (KMP_OFF + KMP_SZ)
#define KV_SZ   (16*6*64*64)             // 393,216
#define KM_OFF  (KV_OFF + KV_SZ)
#define KM_SZ   (16*6*64)
#define WH_OFF  (KM_OFF + KM_SZ)         // ushort storage area (2 floats hold 4 ushorts)
#define WSPLIT_N (2*384*192)             // 147456 elements

__device__ __forceinline__ void bsplit(float f, ushort& h, ushort& l) {
    uint u = __float_as_uint(f);
    uint hr = (u + 0x7FFFu + ((u >> 16) & 1u)) >> 16;
    h = (ushort)hr;
    float fh = __uint_as_float(hr << 16);
    float fl = f - fh;
    uint v = __float_as_uint(fl);
    l = (ushort)((v + 0x7FFFu + ((v >> 16) & 1u)) >> 16);
}

// ---------------- P0: split qk_w into bf16 hi/lo planes ([g][o][k], k contiguous)
__global__ __launch_bounds__(256) void p0_wsplit(
    const float* __restrict__ qk_w, ushort* __restrict__ wh, ushort* __restrict__ wl)
{
    int idx = blockIdx.x * 256 + threadIdx.x;
    if (idx >= WSPLIT_N) return;
    ushort h, l;
    bsplit(qk_w[idx], h, l);
    wh[idx] = h;
    wl[idx] = l;
}

// ---------------- K1: qk GEMM via bf16-split MFMA.
// Per (b,g): C[o=384][n=3136] = W[384x192] @ X[192x3136], epilogue BN + elu+1.
// Block tile 128(o) x 64(n), BK=64, 4 waves (2x2), wave tile 64x32.
__global__ __launch_bounds__(256) void k1_qk_mfma(
    const float* __restrict__ x, const ushort* __restrict__ wh, const ushort* __restrict__ wl,
    const float* __restrict__ gamma, const float* __restrict__ beta,
    const float* __restrict__ mean, const float* __restrict__ var,
    float* __restrict__ qk_out)
{
    __shared__ __align__(16) ushort Ah[8192];   // 128 rows x 8 chunks x 8 bf16
    __shared__ __align__(16) ushort Al[8192];
    __shared__ __align__(16) ushort Bh[4096];   // 64 rows x 8 chunks x 8 bf16
    __shared__ __align__(16) ushort Bl[4096];

    const int bx = blockIdx.x;           // 49 n-tiles
    const int by = blockIdx.y;           // 3 o-tiles (128 each)
    const int bz = blockIdx.z;           // b*2+g
    const int b = bz >> 1, gg = bz & 1;
    const int t = threadIdx.x;
    const int lane = t & 63, wv = t >> 6;
    const int wr = wv >> 1, wc = wv & 1;
    const int lg = lane >> 4, l15 = lane & 15;

    f32x4 acc[4][2];
    #pragma unroll
    for (int m = 0; m < 4; ++m)
        #pragma unroll
        for (int nf = 0; nf < 2; ++nf)
            acc[m][nf] = (f32x4){0.f, 0.f, 0.f, 0.f};

    const float* xg = x + (size_t)(b * 384 + gg * 192) * N_SP + bx * 64;
    const ushort* whg = wh + (gg * 384 + by * 128) * 192;
    const ushort* wlg = wl + (gg * 384 + by * 128) * 192;

    for (int kt = 0; kt < 3; ++kt) {
        // ---- stage A (bf16 hi/lo rows of W, k contiguous): 1024 chunks per array
        #pragma unroll
        for (int li = 0; li < 4; ++li) {
            int c = li * 256 + t;            // chunk id 0..1023
            int row = c >> 3, kb = c & 7;
            int goff = row * 192 + kt * 64 + kb * 8;   // ushort offset
            float4 vh = *(const float4*)(whg + goff);
            float4 vl = *(const float4*)(wlg + goff);
            int ch = (row * 8 + (kb ^ (row & 7))) * 8;
            *(float4*)&Ah[ch] = vh;
            *(float4*)&Al[ch] = vl;
        }
        // ---- stage B: transpose+split X[k][n] -> Bs[n][k] (paired-k u32 writes)
        #pragma unroll
        for (int li = 0; li < 2; ++li) {
            int idx = li * 256 + t;          // 0..511
            int kp = idx >> 4;               // 0..31
            int nq = idx & 15;
            int k0 = kp * 2;
            const float* px = xg + (size_t)(kt * 64 + k0) * N_SP + nq * 4;
            float4 v0 = *(const float4*)px;
            float4 v1 = *(const float4*)(px + N_SP);
            ushort h0[4], l0[4], h1[4], l1[4];
            float a0[4] = {v0.x, v0.y, v0.z, v0.w};
            float a1[4] = {v1.x, v1.y, v1.z, v1.w};
            #pragma unroll
            for (int i = 0; i < 4; ++i) { bsplit(a0[i], h0[i], l0[i]); bsplit(a1[i], h1[i], l1[i]); }
            int kb = k0 >> 3, ks = (k0 & 6) >> 1;
            #pragma unroll
            for (int i = 0; i < 4; ++i) {
                int n = nq * 4 + i;
                int chunk = n * 8 + (kb ^ ((n >> 1) & 7));
                ((uint*)Bh)[chunk * 4 + ks] = (uint)h0[i] | ((uint)h1[i] << 16);
                ((uint*)Bl)[chunk * 4 + ks] = (uint)l0[i] | ((uint)l1[i] << 16);
            }
        }
        __syncthreads();
        // ---- compute: 2 k32-steps
        #pragma unroll
        for (int s = 0; s < 2; ++s) {
            short8 ah[4], al[4], bh[2], bl[2];
            int kb = s * 4 + lg;
            #pragma unroll
            for (int m = 0; m < 4; ++m) {
                int row = wr * 64 + m * 16 + l15;
                int ch = (row * 8 + (kb ^ (row & 7))) * 8;
                ah[m] = *(const short8*)&Ah[ch];
                al[m] = *(const short8*)&Al[ch];
            }
            #pragma unroll
            for (int nf = 0; nf < 2; ++nf) {
                int n = wc * 32 + nf * 16 + l15;
                int ch = (n * 8 + (kb ^ ((n >> 1) & 7))) * 8;
                bh[nf] = *(const short8*)&Bh[ch];
                bl[nf] = *(const short8*)&Bl[ch];
            }
            #pragma unroll
            for (int m = 0; m < 4; ++m)
                #pragma unroll
                for (int nf = 0; nf < 2; ++nf) {
                    acc[m][nf] = __builtin_amdgcn_mfma_f32_16x16x32_bf16(ah[m], bh[nf], acc[m][nf], 0, 0, 0);
                    acc[m][nf] = __builtin_amdgcn_mfma_f32_16x16x32_bf16(ah[m], bl[nf], acc[m][nf], 0, 0, 0);
                    acc[m][nf] = __builtin_amdgcn_mfma_f32_16x16x32_bf16(al[m], bh[nf], acc[m][nf], 0, 0, 0);
                }
        }
        __syncthreads();
    }

    // ---- BN params into LDS (reuse Bh)
    float* scs = (float*)Bh;
    float* shs = scs + 128;
    if (t < 128) {
        int ch = gg * 384 + by * 128 + t;
        float sc = gamma[ch] / sqrtf(var[ch] + BN_EPS);
        scs[t] = sc;
        shs[t] = beta[ch] - mean[ch] * sc;
    }
    __syncthreads();

    size_t obase = ((size_t)(b * 2 + gg) * 384 + by * 128) * N_SP + bx * 64 + wc * 32;
    #pragma unroll
    for (int m = 0; m < 4; ++m)
        #pragma unroll
        for (int nf = 0; nf < 2; ++nf) {
            #pragma unroll
            for (int r = 0; r < 4; ++r) {
                int orow = wr * 64 + m * 16 + lg * 4 + r;
                float v = acc[m][nf][r] * scs[orow] + shs[orow];
                v = v > 0.f ? v + 1.f : __expf(v);
                qk_out[obase + (size_t)orow * N_SP + nf * 16 + l15] = v;
            }
        }
}

// ---------------- K2: per (b,h,chunk): partial kv[d][e] = sum_n k[d,n]*v[e,n]; partial km[d]
__global__ __launch_bounds__(256) void k2_kv(
    const float* __restrict__ x, const float* __restrict__ qk,
    float* __restrict__ kv_part, float* __restrict__ km_part)
{
    __shared__ float ks[64][68];  // [n][d]
    __shared__ float vs[64][68];  // [n][e]
    const int chunk = blockIdx.x;      // 7
    const int h = blockIdx.y, b = blockIdx.z;
    const int t = threadIdx.x, tx = t & 15, ty = t >> 4;
    const float* kp = qk + ((b*2+1)*384 + h*64)*N_SP;
    const float* vp = x  + (b*384 + h*64)*N_SP;
    float acc[4][4] = {};
    float kmacc[4] = {};
    for (int sub = 0; sub < 7; ++sub) {
        int n0 = chunk*448 + sub*64;
        #pragma unroll
        for (int l = 0; l < 4; ++l) {
            int idx = t + l*256;
            int d = idx >> 4, c = idx & 15;
            float4 v4 = *(const float4*)&kp[d*N_SP + n0 + c*4];
            ks[c*4+0][d] = v4.x; ks[c*4+1][d] = v4.y;
            ks[c*4+2][d] = v4.z; ks[c*4+3][d] = v4.w;
        }
        #pragma unroll
        for (int l = 0; l < 4; ++l) {
            int idx = t + l*256;
            int e = idx >> 4, c = idx & 15;
            float4 v4 = *(const float4*)&vp[e*N_SP + n0 + c*4];
            vs[c*4+0][e] = v4.x; vs[c*4+1][e] = v4.y;
            vs[c*4+2][e] = v4.z; vs[c*4+3][e] = v4.w;
        }
        __syncthreads();
        #pragma unroll 8
        for (int n = 0; n < 64; ++n) {
            float4 kd = *(const float4*)&ks[n][ty*4];
            float4 ve = *(const float4*)&vs[n][tx*4];
            float kk[4] = {kd.x,kd.y,kd.z,kd.w}, vv[4] = {ve.x,ve.y,ve.z,ve.w};
            #pragma unroll
            for (int i = 0; i < 4; ++i) {
                kmacc[i] += kk[i];
                #pragma unroll
                for (int j = 0; j < 4; ++j) acc[i][j] += kk[i]*vv[j];
            }
        }
        __syncthreads();
    }
    const int base = ((b*6+h)*7 + chunk)*4096;
    #pragma unroll
    for (int i = 0; i < 4; ++i) {
        float4 r = make_float4(acc[i][0], acc[i][1], acc[i][2], acc[i][3]);
        *(float4*)&kv_part[base + (ty*4+i)*64 + tx*4] = r;
    }
    if (tx == 0) {
        const int kb = ((b*6+h)*7 + chunk)*64;
        #pragma unroll
        for (int i = 0; i < 4; ++i) km_part[kb + ty*4+i] = kmacc[i];
    }
}

// ---------------- K2b: reduce partials; kv *= 1/N (= s^2), km = mean
__global__ __launch_bounds__(256) void k2b_reduce(
    const float* __restrict__ kv_part, const float* __restrict__ km_part,
    float* __restrict__ kv, float* __restrict__ km)
{
    int idx = blockIdx.x*256 + threadIdx.x;
    const float inv_n = 1.0f / (float)N_SP;
    if (idx < 16*6*64*64) {
        int bh = idx >> 12, de = idx & 4095;
        float s = 0.f;
        #pragma unroll
        for (int c = 0; c < 7; ++c) s += kv_part[(bh*7+c)*4096 + de];
        kv[idx] = s * inv_n;
    }
    if (idx < 16*6*64) {
        int bh = idx >> 6, d = idx & 63;
        float s = 0.f;
        #pragma unroll
        for (int c = 0; c < 7; ++c) s += km_part[(bh*7+c)*64 + d];
        km[idx] = s * inv_n;
    }
}

// ---------------- K3: attn out + fused depthwise 3x3 conv + BN (pe) added
__global__ __launch_bounds__(256) void k3_attn_pe(
    const float* __restrict__ x, const float* __restrict__ qk,
    const float* __restrict__ kv, const float* __restrict__ km,
    const float* __restrict__ pw,
    const float* __restrict__ pgamma, const float* __restrict__ pbeta,
    const float* __restrict__ pmean, const float* __restrict__ pvar,
    float* __restrict__ out)
{
    __shared__ float qs[64][68];   // [d][n]
    __shared__ float kvs[64][68];  // [d][e]
    __shared__ float kms[64];
    const int bx = blockIdx.x;    // 49 n tiles
    const int h = blockIdx.y, b = blockIdx.z;
    const int t = threadIdx.x, tx = t & 15, ty = t >> 4;
    const int n0 = bx*64;
    const float* qp  = qk + ((b*2+0)*384 + h*64)*N_SP;
    const float* kvp = kv + (b*6+h)*4096;
    #pragma unroll
    for (int l = 0; l < 4; ++l) {
        int idx = t + l*256;
        int d = idx >> 4, c = idx & 15;
        *(float4*)&qs[d][c*4] = *(const float4*)&qp[d*N_SP + n0 + c*4];
    }
    #pragma unroll
    for (int l = 0; l < 4; ++l) {
        int idx = t + l*256;
        int d = idx >> 4, c = idx & 15;
        *(float4*)&kvs[d][c*4] = *(const float4*)&kvp[d*64 + c*4];
    }
    if (t < 64) kms[t] = km[(b*6+h)*64 + t];
    __syncthreads();
    float acc[4][4] = {};
    float den[4] = {};
    #pragma unroll 8
    for (int d = 0; d < 64; ++d) {
        float4 qn = *(const float4*)&qs[d][ty*4];
        float4 ke = *(const float4*)&kvs[d][tx*4];
        float qq[4] = {qn.x,qn.y,qn.z,qn.w}, kk[4] = {ke.x,ke.y,ke.z,ke.w};
        float kmd = kms[d];
        #pragma unroll
        for (int i = 0; i < 4; ++i) {
            den[i] += qq[i]*kmd;
            #pragma unroll
            for (int j = 0; j < 4; ++j) acc[i][j] += qq[i]*kk[j];
        }
    }
    // fused conv: this thread's pixels are n0+ty*4 .. +3 (one image row; 56%4==0)
    const int nb = n0 + ty*4;
    const int y = nb / 56, xc = nb % 56;
    #pragma unroll
    for (int j = 0; j < 4; ++j) {
        int c = h*64 + tx*4 + j;
        const float* xp = x + ((size_t)b*384 + c)*N_SP;
        float seg[3][6];
        #pragma unroll
        for (int dy = 0; dy < 3; ++dy) {
            int yy = y + dy - 1;
            bool yok = (yy >= 0) && (yy < 56);
            #pragma unroll
            for (int s = 0; s < 6; ++s) {
                int col = xc - 1 + s;
                seg[dy][s] = (yok && col >= 0 && col < 56) ? xp[yy*56 + col] : 0.f;
            }
        }
        float w9[9];
        #pragma unroll
        for (int q = 0; q < 9; ++q) w9[q] = pw[c*9 + q];
        float sc2 = pgamma[c] / sqrtf(pvar[c] + BN_EPS);
        float sh2 = pbeta[c] - pmean[c]*sc2;
        float4 r;
        float* pr = (float*)&r;
        #pragma unroll
        for (int p = 0; p < 4; ++p) {
            float conv = 0.f;
            #pragma unroll
            for (int dy = 0; dy < 3; ++dy)
                #pragma unroll
                for (int dx = 0; dx < 3; ++dx)
                    conv += w9[dy*3+dx] * seg[dy][p + dx];
            pr[p] = acc[p][j] / (den[p] + 1e-6f) + (conv*sc2 + sh2);
        }
        *(float4*)&out[((size_t)b*384 + c)*N_SP + n0 + ty*4] = r;
    }
}

extern "C" void kernel_launch(void* const* d_in, const int* in_sizes, int n_in,
                              void* d_out, int out_size, void* d_ws, size_t ws_size,
                              hipStream_t stream)
{
    const float* x        = (const float*)d_in[0];
    const float* qk_w     = (const float*)d_in[1];
    const float* qk_gamma = (const float*)d_in[2];
    const float* qk_beta  = (const float*)d_in[3];
    const float* qk_mean  = (const float*)d_in[4];
    const float* qk_var   = (const float*)d_in[5];
    const float* pe_w     = (const float*)d_in[6];
    const float* pe_gamma = (const float*)d_in[7];
    const float* pe_beta  = (const float*)d_in[8];
    const float* pe_mean  = (const float*)d_in[9];
    const float* pe_var   = (const float*)d_in[10];
    float* out = (float*)d_out;

    float* ws      = (float*)d_ws;
    float* qk      = ws;
    float* kv_part = ws + KVP_OFF;
    float* km_part = ws + KMP_OFF;
    float* kv      = ws + KV_OFF;
    float* km      = ws + KM_OFF;
    ushort* whp    = (ushort*)(ws + WH_OFF);
    ushort* wlp    = whp + WSPLIT_N;

    hipLaunchKernelGGL(p0_wsplit, dim3((WSPLIT_N + 255)/256), dim3(256), 0, stream,
                       qk_w, whp, wlp);
    dim3 g1(49, 3, 32);
    hipLaunchKernelGGL(k1_qk_mfma, g1, dim3(256), 0, stream,
                       x, whp, wlp, qk_gamma, qk_beta, qk_mean, qk_var, qk);
    dim3 g2(7, 6, 16);
    hipLaunchKernelGGL(k2_kv, g2, dim3(256), 0, stream, x, qk, kv_part, km_part);
    hipLaunchKernelGGL(k2b_reduce, dim3(1536), dim3(256), 0, stream,
                       kv_part, km_part, kv, km);
    dim3 g3(49, 6, 16);
    hipLaunchKernelGGL(k3_attn_pe, g3, dim3(256), 0, stream,
                       x, qk, kv, km, pe_w, pe_gamma, pe_beta, pe_mean, pe_var, out);
}

// Round 3
// 241.931 us; speedup vs baseline: 1.9578x; 1.3275x over previous
//
#include <hip/hip_runtime.h>
#include <math.h>

#define N_SP 3136
#define BN_EPS 1e-5f

typedef __attribute__((ext_vector_type(8))) short short8;
typedef __attribute__((ext_vector_type(4))) float f32x4;

// ws layout (float elements)
#define QK_SZ   (16*2*384*N_SP)          // 38,535,168
#define KVP_OFF (QK_SZ)
#define KVP_SZ  (16*6*7*64*64)           // 2,752,512
#define KMP_OFF (KVP_OFF + KVP_SZ)
#define KMP_SZ  (16*6*7*64)              // 43,008
#define KV_OFF  (KMP_OFF + KMP_SZ)
#define KV_SZ   (16*6*64*64)             // 393,216
#define KM_OFF  (KV_OFF + KV_SZ)
#define KM_SZ   (16*6*64)
#define WH_OFF  (KM_OFF + KM_SZ)         // ushort storage area (2 floats hold 4 ushorts)
#define WSPLIT_N (2*384*192)             // 147456 elements

__device__ __forceinline__ void bsplit(float f, ushort& h, ushort& l) {
    uint u = __float_as_uint(f);
    uint hr = (u + 0x7FFFu + ((u >> 16) & 1u)) >> 16;
    h = (ushort)hr;
    float fh = __uint_as_float(hr << 16);
    float fl = f - fh;
    uint v = __float_as_uint(fl);
    l = (ushort)((v + 0x7FFFu + ((v >> 16) & 1u)) >> 16);
}

// ---------------- P0: split qk_w into bf16 hi/lo planes ([g][o][k], k contiguous)
__global__ __launch_bounds__(256) void p0_wsplit(
    const float* __restrict__ qk_w, ushort* __restrict__ wh, ushort* __restrict__ wl)
{
    int idx = blockIdx.x * 256 + threadIdx.x;
    if (idx >= WSPLIT_N) return;
    ushort h, l;
    bsplit(qk_w[idx], h, l);
    wh[idx] = h;
    wl[idx] = l;
}

// ---------------- K1: qk GEMM via bf16-split MFMA.
__global__ __launch_bounds__(256) void k1_qk_mfma(
    const float* __restrict__ x, const ushort* __restrict__ wh, const ushort* __restrict__ wl,
    const float* __restrict__ gamma, const float* __restrict__ beta,
    const float* __restrict__ mean, const float* __restrict__ var,
    float* __restrict__ qk_out)
{
    __shared__ __align__(16) ushort Ah[8192];   // 128 rows x 8 chunks x 8 bf16
    __shared__ __align__(16) ushort Al[8192];
    __shared__ __align__(16) ushort Bh[4096];   // 64 rows x 8 chunks x 8 bf16
    __shared__ __align__(16) ushort Bl[4096];

    const int bx = blockIdx.x;           // 49 n-tiles
    const int by = blockIdx.y;           // 3 o-tiles (128 each)
    const int bz = blockIdx.z;           // b*2+g
    const int b = bz >> 1, gg = bz & 1;
    const int t = threadIdx.x;
    const int lane = t & 63, wv = t >> 6;
    const int wr = wv >> 1, wc = wv & 1;
    const int lg = lane >> 4, l15 = lane & 15;

    f32x4 acc[4][2];
    #pragma unroll
    for (int m = 0; m < 4; ++m)
        #pragma unroll
        for (int nf = 0; nf < 2; ++nf)
            acc[m][nf] = (f32x4){0.f, 0.f, 0.f, 0.f};

    const float* xg = x + (size_t)(b * 384 + gg * 192) * N_SP + bx * 64;
    const ushort* whg = wh + (gg * 384 + by * 128) * 192;
    const ushort* wlg = wl + (gg * 384 + by * 128) * 192;

    for (int kt = 0; kt < 3; ++kt) {
        #pragma unroll
        for (int li = 0; li < 4; ++li) {
            int c = li * 256 + t;            // chunk id 0..1023
            int row = c >> 3, kb = c & 7;
            int goff = row * 192 + kt * 64 + kb * 8;   // ushort offset
            float4 vh = *(const float4*)(whg + goff);
            float4 vl = *(const float4*)(wlg + goff);
            int ch = (row * 8 + (kb ^ (row & 7))) * 8;
            *(float4*)&Ah[ch] = vh;
            *(float4*)&Al[ch] = vl;
        }
        #pragma unroll
        for (int li = 0; li < 2; ++li) {
            int idx = li * 256 + t;          // 0..511
            int kp = idx >> 4;               // 0..31
            int nq = idx & 15;
            int k0 = kp * 2;
            const float* px = xg + (size_t)(kt * 64 + k0) * N_SP + nq * 4;
            float4 v0 = *(const float4*)px;
            float4 v1 = *(const float4*)(px + N_SP);
            ushort h0[4], l0[4], h1[4], l1[4];
            float a0[4] = {v0.x, v0.y, v0.z, v0.w};
            float a1[4] = {v1.x, v1.y, v1.z, v1.w};
            #pragma unroll
            for (int i = 0; i < 4; ++i) { bsplit(a0[i], h0[i], l0[i]); bsplit(a1[i], h1[i], l1[i]); }
            int kb = k0 >> 3, ks = (k0 & 6) >> 1;
            #pragma unroll
            for (int i = 0; i < 4; ++i) {
                int n = nq * 4 + i;
                int chunk = n * 8 + (kb ^ ((n >> 1) & 7));
                ((uint*)Bh)[chunk * 4 + ks] = (uint)h0[i] | ((uint)h1[i] << 16);
                ((uint*)Bl)[chunk * 4 + ks] = (uint)l0[i] | ((uint)l1[i] << 16);
            }
        }
        __syncthreads();
        #pragma unroll
        for (int s = 0; s < 2; ++s) {
            short8 ah[4], al[4], bh[2], bl[2];
            int kb = s * 4 + lg;
            #pragma unroll
            for (int m = 0; m < 4; ++m) {
                int row = wr * 64 + m * 16 + l15;
                int ch = (row * 8 + (kb ^ (row & 7))) * 8;
                ah[m] = *(const short8*)&Ah[ch];
                al[m] = *(const short8*)&Al[ch];
            }
            #pragma unroll
            for (int nf = 0; nf < 2; ++nf) {
                int n = wc * 32 + nf * 16 + l15;
                int ch = (n * 8 + (kb ^ ((n >> 1) & 7))) * 8;
                bh[nf] = *(const short8*)&Bh[ch];
                bl[nf] = *(const short8*)&Bl[ch];
            }
            #pragma unroll
            for (int m = 0; m < 4; ++m)
                #pragma unroll
                for (int nf = 0; nf < 2; ++nf) {
                    acc[m][nf] = __builtin_amdgcn_mfma_f32_16x16x32_bf16(ah[m], bh[nf], acc[m][nf], 0, 0, 0);
                    acc[m][nf] = __builtin_amdgcn_mfma_f32_16x16x32_bf16(ah[m], bl[nf], acc[m][nf], 0, 0, 0);
                    acc[m][nf] = __builtin_amdgcn_mfma_f32_16x16x32_bf16(al[m], bh[nf], acc[m][nf], 0, 0, 0);
                }
        }
        __syncthreads();
    }

    float* scs = (float*)Bh;
    float* shs = scs + 128;
    if (t < 128) {
        int ch = gg * 384 + by * 128 + t;
        float sc = gamma[ch] / sqrtf(var[ch] + BN_EPS);
        scs[t] = sc;
        shs[t] = beta[ch] - mean[ch] * sc;
    }
    __syncthreads();

    size_t obase = ((size_t)(b * 2 + gg) * 384 + by * 128) * N_SP + bx * 64 + wc * 32;
    #pragma unroll
    for (int m = 0; m < 4; ++m)
        #pragma unroll
        for (int nf = 0; nf < 2; ++nf) {
            #pragma unroll
            for (int r = 0; r < 4; ++r) {
                int orow = wr * 64 + m * 16 + lg * 4 + r;
                float v = acc[m][nf][r] * scs[orow] + shs[orow];
                v = v > 0.f ? v + 1.f : __expf(v);
                qk_out[obase + (size_t)orow * N_SP + nf * 16 + l15] = v;
            }
        }
}

// ---------------- K2: per (b,h,chunk): partial kv[d][e] = sum_n k[d,n]*v[e,n]; partial km[d]
__global__ __launch_bounds__(256) void k2_kv(
    const float* __restrict__ x, const float* __restrict__ qk,
    float* __restrict__ kv_part, float* __restrict__ km_part)
{
    __shared__ float ks[64][68];  // [n][d]
    __shared__ float vs[64][68];  // [n][e]
    const int chunk = blockIdx.x;      // 7
    const int h = blockIdx.y, b = blockIdx.z;
    const int t = threadIdx.x, tx = t & 15, ty = t >> 4;
    const float* kp = qk + ((b*2+1)*384 + h*64)*N_SP;
    const float* vp = x  + (b*384 + h*64)*N_SP;
    float acc[4][4] = {};
    float kmacc[4] = {};
    for (int sub = 0; sub < 7; ++sub) {
        int n0 = chunk*448 + sub*64;
        #pragma unroll
        for (int l = 0; l < 4; ++l) {
            int idx = t + l*256;
            int d = idx >> 4, c = idx & 15;
            float4 v4 = *(const float4*)&kp[d*N_SP + n0 + c*4];
            ks[c*4+0][d] = v4.x; ks[c*4+1][d] = v4.y;
            ks[c*4+2][d] = v4.z; ks[c*4+3][d] = v4.w;
        }
        #pragma unroll
        for (int l = 0; l < 4; ++l) {
            int idx = t + l*256;
            int e = idx >> 4, c = idx & 15;
            float4 v4 = *(const float4*)&vp[e*N_SP + n0 + c*4];
            vs[c*4+0][e] = v4.x; vs[c*4+1][e] = v4.y;
            vs[c*4+2][e] = v4.z; vs[c*4+3][e] = v4.w;
        }
        __syncthreads();
        #pragma unroll 8
        for (int n = 0; n < 64; ++n) {
            float4 kd = *(const float4*)&ks[n][ty*4];
            float4 ve = *(const float4*)&vs[n][tx*4];
            float kk[4] = {kd.x,kd.y,kd.z,kd.w}, vv[4] = {ve.x,ve.y,ve.z,ve.w};
            #pragma unroll
            for (int i = 0; i < 4; ++i) {
                kmacc[i] += kk[i];
                #pragma unroll
                for (int j = 0; j < 4; ++j) acc[i][j] += kk[i]*vv[j];
            }
        }
        __syncthreads();
    }
    const int base = ((b*6+h)*7 + chunk)*4096;
    #pragma unroll
    for (int i = 0; i < 4; ++i) {
        float4 r = make_float4(acc[i][0], acc[i][1], acc[i][2], acc[i][3]);
        *(float4*)&kv_part[base + (ty*4+i)*64 + tx*4] = r;
    }
    if (tx == 0) {
        const int kb = ((b*6+h)*7 + chunk)*64;
        #pragma unroll
        for (int i = 0; i < 4; ++i) km_part[kb + ty*4+i] = kmacc[i];
    }
}

// ---------------- K2b: reduce partials; kv *= 1/N (= s^2), km = mean
__global__ __launch_bounds__(256) void k2b_reduce(
    const float* __restrict__ kv_part, const float* __restrict__ km_part,
    float* __restrict__ kv, float* __restrict__ km)
{
    int idx = blockIdx.x*256 + threadIdx.x;
    const float inv_n = 1.0f / (float)N_SP;
    if (idx < 16*6*64*64) {
        int bh = idx >> 12, de = idx & 4095;
        float s = 0.f;
        #pragma unroll
        for (int c = 0; c < 7; ++c) s += kv_part[(bh*7+c)*4096 + de];
        kv[idx] = s * inv_n;
    }
    if (idx < 16*6*64) {
        int bh = idx >> 6, d = idx & 63;
        float s = 0.f;
        #pragma unroll
        for (int c = 0; c < 7; ++c) s += km_part[(bh*7+c)*64 + d];
        km[idx] = s * inv_n;
    }
}

// ---------------- K3: attn out + fused depthwise 3x3 conv + BN (pe).
// Lane map: tx (0..15) -> pixels (4 consecutive), ty (0..15) -> channels (4 each).
__global__ __launch_bounds__(256) void k3_attn_pe(
    const float* __restrict__ x, const float* __restrict__ qk,
    const float* __restrict__ kv, const float* __restrict__ km,
    const float* __restrict__ pw,
    const float* __restrict__ pgamma, const float* __restrict__ pbeta,
    const float* __restrict__ pmean, const float* __restrict__ pvar,
    float* __restrict__ out)
{
    __shared__ float qs[64][68];   // [d][n]
    __shared__ float kvs[64][68];  // [d][e]
    __shared__ float kms[64];
    const int bx = blockIdx.x;    // 49 n tiles
    const int h = blockIdx.y, b = blockIdx.z;
    const int t = threadIdx.x, tx = t & 15, ty = t >> 4;
    const int n0 = bx*64;
    const float* qp  = qk + ((b*2+0)*384 + h*64)*N_SP;
    const float* kvp = kv + (b*6+h)*4096;
    #pragma unroll
    for (int l = 0; l < 4; ++l) {
        int idx = t + l*256;
        int d = idx >> 4, c = idx & 15;
        *(float4*)&qs[d][c*4] = *(const float4*)&qp[d*N_SP + n0 + c*4];
    }
    #pragma unroll
    for (int l = 0; l < 4; ++l) {
        int idx = t + l*256;
        int d = idx >> 4, c = idx & 15;
        *(float4*)&kvs[d][c*4] = *(const float4*)&kvp[d*64 + c*4];
    }
    if (t < 64) kms[t] = km[(b*6+h)*64 + t];
    __syncthreads();

    float acc[4][4] = {};   // [p=pixel][j=channel]
    float den[4] = {};
    #pragma unroll 8
    for (int d = 0; d < 64; ++d) {
        float4 qn = *(const float4*)&qs[d][tx*4];    // 4 pixels
        float4 ke = *(const float4*)&kvs[d][ty*4];   // 4 channels
        float qq[4] = {qn.x,qn.y,qn.z,qn.w}, kk[4] = {ke.x,ke.y,ke.z,ke.w};
        float kmd = kms[d];
        #pragma unroll
        for (int p = 0; p < 4; ++p) {
            den[p] += qq[p]*kmd;
            #pragma unroll
            for (int j = 0; j < 4; ++j) acc[p][j] += qq[p]*kk[j];
        }
    }

    // conv + epilogue: this thread's pixels n0+tx*4 .. +3 (single image row; 56%4==0)
    const int p0 = n0 + tx*4;
    const int y = p0 / 56, xc = p0 % 56;
    #pragma unroll
    for (int j = 0; j < 4; ++j) {
        int c = h*64 + ty*4 + j;
        const float* xp = x + ((size_t)b*384 + c)*N_SP;
        float seg[3][6];
        #pragma unroll
        for (int dy = 0; dy < 3; ++dy) {
            int yy = y + dy - 1;
            bool yok = (yy >= 0) && (yy < 56);
            const float* xr = xp + yy*56;
            #pragma unroll
            for (int s = 0; s < 6; ++s) {
                int col = xc - 1 + s;
                seg[dy][s] = (yok && col >= 0 && col < 56) ? xr[col] : 0.f;
            }
        }
        float w9[9];
        #pragma unroll
        for (int q = 0; q < 9; ++q) w9[q] = pw[c*9 + q];
        float sc2 = pgamma[c] / sqrtf(pvar[c] + BN_EPS);
        float sh2 = pbeta[c] - pmean[c]*sc2;
        float4 r;
        float* pr = (float*)&r;
        #pragma unroll
        for (int p = 0; p < 4; ++p) {
            float conv = 0.f;
            #pragma unroll
            for (int dy = 0; dy < 3; ++dy)
                #pragma unroll
                for (int dx = 0; dx < 3; ++dx)
                    conv += w9[dy*3+dx] * seg[dy][p + dx];
            pr[p] = acc[p][j] / (den[p] + 1e-6f) + (conv*sc2 + sh2);
        }
        *(float4*)&out[((size_t)b*384 + c)*N_SP + p0] = r;
    }
}

extern "C" void kernel_launch(void* const* d_in, const int* in_sizes, int n_in,
                              void* d_out, int out_size, void* d_ws, size_t ws_size,
                              hipStream_t stream)
{
    const float* x        = (const float*)d_in[0];
    const float* qk_w     = (const float*)d_in[1];
    const float* qk_gamma = (const float*)d_in[2];
    const float* qk_beta  = (const float*)d_in[3];
    const float* qk_mean  = (const float*)d_in[4];
    const float* qk_var   = (const float*)d_in[5];
    const float* pe_w     = (const float*)d_in[6];
    const float* pe_gamma = (const float*)d_in[7];
    const float* pe_beta  = (const float*)d_in[8];
    const float* pe_mean  = (const float*)d_in[9];
    const float* pe_var   = (const float*)d_in[10];
    float* out = (float*)d_out;

    float* ws      = (float*)d_ws;
    float* qk      = ws;
    float* kv_part = ws + KVP_OFF;
    float* km_part = ws + KMP_OFF;
    float* kv      = ws + KV_OFF;
    float* km      = ws + KM_OFF;
    ushort* whp    = (ushort*)(ws + WH_OFF);
    ushort* wlp    = whp + WSPLIT_N;

    hipLaunchKernelGGL(p0_wsplit, dim3((WSPLIT_N + 255)/256), dim3(256), 0, stream,
                       qk_w, whp, wlp);
    dim3 g1(49, 3, 32);
    hipLaunchKernelGGL(k1_qk_mfma, g1, dim3(256), 0, stream,
                       x, whp, wlp, qk_gamma, qk_beta, qk_mean, qk_var, qk);
    dim3 g2(7, 6, 16);
    hipLaunchKernelGGL(k2_kv, g2, dim3(256), 0, stream, x, qk, kv_part, km_part);
    hipLaunchKernelGGL(k2b_reduce, dim3(1536), dim3(256), 0, stream,
                       kv_part, km_part, kv, km);
    dim3 g3(49, 6, 16);
    hipLaunchKernelGGL(k3_attn_pe, g3, dim3(256), 0, stream,
                       x, qk, kv, km, pe_w, pe_gamma, pe_beta, pe_mean, pe_var, out);
}

// Round 4
// 219.848 us; speedup vs baseline: 2.1545x; 1.1004x over previous
//
#include <hip/hip_runtime.h>
#include <math.h>

#define N_SP 3136
#define BN_EPS 1e-5f

typedef __attribute__((ext_vector_type(8))) short short8;
typedef __attribute__((ext_vector_type(4))) float f32x4;

// ws layout (float elements)
#define QK_SZ   (16*2*384*N_SP)          // 38,535,168
#define KVP_OFF (QK_SZ)
#define KVP_SZ  (16*6*7*64*80)           // 3,440,640  ([d][80]: cols 0..63 kv, col 64 = sum_k)
#define KV_OFF  (KVP_OFF + KVP_SZ)
#define KV_SZ   (16*6*64*64)             // 393,216
#define KM_OFF  (KV_OFF + KV_SZ)
#define KM_SZ   (16*6*64)
#define WH_OFF  (KM_OFF + KM_SZ)         // ushort storage area
#define WSPLIT_N (2*384*192)             // 147456 elements

__device__ __forceinline__ void bsplit(float f, ushort& h, ushort& l) {
    uint u = __float_as_uint(f);
    uint hr = (u + 0x7FFFu + ((u >> 16) & 1u)) >> 16;
    h = (ushort)hr;
    float fh = __uint_as_float(hr << 16);
    float fl = f - fh;
    uint v = __float_as_uint(fl);
    l = (ushort)((v + 0x7FFFu + ((v >> 16) & 1u)) >> 16);
}

// ---------------- P0: split qk_w into bf16 hi/lo planes ([g][o][k], k contiguous)
__global__ __launch_bounds__(256) void p0_wsplit(
    const float* __restrict__ qk_w, ushort* __restrict__ wh, ushort* __restrict__ wl)
{
    int idx = blockIdx.x * 256 + threadIdx.x;
    if (idx >= WSPLIT_N) return;
    ushort h, l;
    bsplit(qk_w[idx], h, l);
    wh[idx] = h;
    wl[idx] = l;
}

// ---------------- K1: qk GEMM via bf16-split MFMA (unchanged).
__global__ __launch_bounds__(256) void k1_qk_mfma(
    const float* __restrict__ x, const ushort* __restrict__ wh, const ushort* __restrict__ wl,
    const float* __restrict__ gamma, const float* __restrict__ beta,
    const float* __restrict__ mean, const float* __restrict__ var,
    float* __restrict__ qk_out)
{
    __shared__ __align__(16) ushort Ah[8192];
    __shared__ __align__(16) ushort Al[8192];
    __shared__ __align__(16) ushort Bh[4096];
    __shared__ __align__(16) ushort Bl[4096];

    const int bx = blockIdx.x;           // 49 n-tiles
    const int by = blockIdx.y;           // 3 o-tiles (128 each)
    const int bz = blockIdx.z;           // b*2+g
    const int b = bz >> 1, gg = bz & 1;
    const int t = threadIdx.x;
    const int lane = t & 63, wv = t >> 6;
    const int wr = wv >> 1, wc = wv & 1;
    const int lg = lane >> 4, l15 = lane & 15;

    f32x4 acc[4][2];
    #pragma unroll
    for (int m = 0; m < 4; ++m)
        #pragma unroll
        for (int nf = 0; nf < 2; ++nf)
            acc[m][nf] = (f32x4){0.f, 0.f, 0.f, 0.f};

    const float* xg = x + (size_t)(b * 384 + gg * 192) * N_SP + bx * 64;
    const ushort* whg = wh + (gg * 384 + by * 128) * 192;
    const ushort* wlg = wl + (gg * 384 + by * 128) * 192;

    for (int kt = 0; kt < 3; ++kt) {
        #pragma unroll
        for (int li = 0; li < 4; ++li) {
            int c = li * 256 + t;
            int row = c >> 3, kb = c & 7;
            int goff = row * 192 + kt * 64 + kb * 8;
            float4 vh = *(const float4*)(whg + goff);
            float4 vl = *(const float4*)(wlg + goff);
            int ch = (row * 8 + (kb ^ (row & 7))) * 8;
            *(float4*)&Ah[ch] = vh;
            *(float4*)&Al[ch] = vl;
        }
        #pragma unroll
        for (int li = 0; li < 2; ++li) {
            int idx = li * 256 + t;
            int kp = idx >> 4;
            int nq = idx & 15;
            int k0 = kp * 2;
            const float* px = xg + (size_t)(kt * 64 + k0) * N_SP + nq * 4;
            float4 v0 = *(const float4*)px;
            float4 v1 = *(const float4*)(px + N_SP);
            ushort h0[4], l0[4], h1[4], l1[4];
            float a0[4] = {v0.x, v0.y, v0.z, v0.w};
            float a1[4] = {v1.x, v1.y, v1.z, v1.w};
            #pragma unroll
            for (int i = 0; i < 4; ++i) { bsplit(a0[i], h0[i], l0[i]); bsplit(a1[i], h1[i], l1[i]); }
            int kb = k0 >> 3, ks = (k0 & 6) >> 1;
            #pragma unroll
            for (int i = 0; i < 4; ++i) {
                int n = nq * 4 + i;
                int chunk = n * 8 + (kb ^ ((n >> 1) & 7));
                ((uint*)Bh)[chunk * 4 + ks] = (uint)h0[i] | ((uint)h1[i] << 16);
                ((uint*)Bl)[chunk * 4 + ks] = (uint)l0[i] | ((uint)l1[i] << 16);
            }
        }
        __syncthreads();
        #pragma unroll
        for (int s = 0; s < 2; ++s) {
            short8 ah[4], al[4], bh[2], bl[2];
            int kb = s * 4 + lg;
            #pragma unroll
            for (int m = 0; m < 4; ++m) {
                int row = wr * 64 + m * 16 + l15;
                int ch = (row * 8 + (kb ^ (row & 7))) * 8;
                ah[m] = *(const short8*)&Ah[ch];
                al[m] = *(const short8*)&Al[ch];
            }
            #pragma unroll
            for (int nf = 0; nf < 2; ++nf) {
                int n = wc * 32 + nf * 16 + l15;
                int ch = (n * 8 + (kb ^ ((n >> 1) & 7))) * 8;
                bh[nf] = *(const short8*)&Bh[ch];
                bl[nf] = *(const short8*)&Bl[ch];
            }
            #pragma unroll
            for (int m = 0; m < 4; ++m)
                #pragma unroll
                for (int nf = 0; nf < 2; ++nf) {
                    acc[m][nf] = __builtin_amdgcn_mfma_f32_16x16x32_bf16(ah[m], bh[nf], acc[m][nf], 0, 0, 0);
                    acc[m][nf] = __builtin_amdgcn_mfma_f32_16x16x32_bf16(ah[m], bl[nf], acc[m][nf], 0, 0, 0);
                    acc[m][nf] = __builtin_amdgcn_mfma_f32_16x16x32_bf16(al[m], bh[nf], acc[m][nf], 0, 0, 0);
                }
        }
        __syncthreads();
    }

    float* scs = (float*)Bh;
    float* shs = scs + 128;
    if (t < 128) {
        int ch = gg * 384 + by * 128 + t;
        float sc = gamma[ch] / sqrtf(var[ch] + BN_EPS);
        scs[t] = sc;
        shs[t] = beta[ch] - mean[ch] * sc;
    }
    __syncthreads();

    size_t obase = ((size_t)(b * 2 + gg) * 384 + by * 128) * N_SP + bx * 64 + wc * 32;
    #pragma unroll
    for (int m = 0; m < 4; ++m)
        #pragma unroll
        for (int nf = 0; nf < 2; ++nf) {
            #pragma unroll
            for (int r = 0; r < 4; ++r) {
                int orow = wr * 64 + m * 16 + lg * 4 + r;
                float v = acc[m][nf][r] * scs[orow] + shs[orow];
                v = v > 0.f ? v + 1.f : __expf(v);
                qk_out[obase + (size_t)orow * N_SP + nf * 16 + l15] = v;
            }
        }
}

// ---------------- K2: kv + ksum via MFMA. Per (b,h,chunk): D[d][0..63]=sum_n k*v,
// D[d][64]=sum_n k (ones-column). A = k rows (n-contig), B = v rows (n-contig).
__global__ __launch_bounds__(256) void k2_kv_mfma(
    const float* __restrict__ x, const float* __restrict__ qk,
    float* __restrict__ kv_part)
{
    __shared__ __align__(16) ushort Kh[4096], Kl[4096];   // 64 rows x 8 chunks x 8
    __shared__ __align__(16) ushort Vh[5120], Vl[5120];   // 80 rows x 8 chunks x 8

    const int chunk = blockIdx.x;      // 7
    const int h = blockIdx.y, b = blockIdx.z;
    const int t = threadIdx.x;
    const int lane = t & 63, wv = t >> 6;
    const int lg = lane >> 4, l15 = lane & 15;

    const float* kp = qk + (size_t)((b*2+1)*384 + h*64) * N_SP;
    const float* vp = x  + (size_t)(b*384 + h*64) * N_SP;

    // init V rows 64..79: row 64 = ones (bf16 1.0 hi, 0 lo), rows 65..79 = 0
    #pragma unroll
    for (int li = 0; li < 4; ++li) {
        int idx = li * 256 + t;          // 0..1023
        int row = 64 + (idx >> 6), col = idx & 63;
        int off = (row * 8 + ((col >> 3) ^ (row & 7))) * 8 + (col & 7);
        Vh[off] = (row == 64) ? (ushort)0x3F80 : (ushort)0;
        Vl[off] = 0;
    }

    f32x4 acc[5];
    #pragma unroll
    for (int nf = 0; nf < 5; ++nf) acc[nf] = (f32x4){0.f, 0.f, 0.f, 0.f};

    for (int sub = 0; sub < 7; ++sub) {
        int n0 = chunk * 448 + sub * 64;
        // stage K and V (rows 0..63), 4 tasks each per thread
        #pragma unroll
        for (int li = 0; li < 4; ++li) {
            int idx = li * 256 + t;      // 0..1023
            int row = idx >> 4, sc = idx & 15;
            int off = (row * 8 + ((sc >> 1) ^ (row & 7))) * 8 + (sc & 1) * 4;
            float4 kf = *(const float4*)&kp[(size_t)row * N_SP + n0 + sc * 4];
            ushort h0,h1,h2,h3,l0,l1,l2,l3;
            bsplit(kf.x,h0,l0); bsplit(kf.y,h1,l1); bsplit(kf.z,h2,l2); bsplit(kf.w,h3,l3);
            ((uint*)&Kh[off])[0] = (uint)h0 | ((uint)h1 << 16);
            ((uint*)&Kh[off])[1] = (uint)h2 | ((uint)h3 << 16);
            ((uint*)&Kl[off])[0] = (uint)l0 | ((uint)l1 << 16);
            ((uint*)&Kl[off])[1] = (uint)l2 | ((uint)l3 << 16);
            float4 vf = *(const float4*)&vp[(size_t)row * N_SP + n0 + sc * 4];
            bsplit(vf.x,h0,l0); bsplit(vf.y,h1,l1); bsplit(vf.z,h2,l2); bsplit(vf.w,h3,l3);
            ((uint*)&Vh[off])[0] = (uint)h0 | ((uint)h1 << 16);
            ((uint*)&Vh[off])[1] = (uint)h2 | ((uint)h3 << 16);
            ((uint*)&Vl[off])[0] = (uint)l0 | ((uint)l1 << 16);
            ((uint*)&Vl[off])[1] = (uint)l2 | ((uint)l3 << 16);
        }
        __syncthreads();
        // compute: wave wv owns A rows wv*16..+15; all 5 B nf-frags
        #pragma unroll
        for (int s = 0; s < 2; ++s) {
            int arow = wv * 16 + l15;
            int akb = (s * 4 + lg) ^ (arow & 7);
            short8 ah = *(const short8*)&Kh[(arow * 8 + akb) * 8];
            short8 al = *(const short8*)&Kl[(arow * 8 + akb) * 8];
            #pragma unroll
            for (int nf = 0; nf < 5; ++nf) {
                int brow = nf * 16 + l15;
                int bkb = (s * 4 + lg) ^ (brow & 7);
                short8 bh = *(const short8*)&Vh[(brow * 8 + bkb) * 8];
                short8 bl = *(const short8*)&Vl[(brow * 8 + bkb) * 8];
                acc[nf] = __builtin_amdgcn_mfma_f32_16x16x32_bf16(ah, bh, acc[nf], 0, 0, 0);
                acc[nf] = __builtin_amdgcn_mfma_f32_16x16x32_bf16(ah, bl, acc[nf], 0, 0, 0);
                acc[nf] = __builtin_amdgcn_mfma_f32_16x16x32_bf16(al, bh, acc[nf], 0, 0, 0);
            }
        }
        __syncthreads();
    }

    size_t base = (size_t)((b*6 + h)*7 + chunk) * 64 * 80;
    #pragma unroll
    for (int nf = 0; nf < 5; ++nf)
        #pragma unroll
        for (int r = 0; r < 4; ++r) {
            int d = wv * 16 + lg * 4 + r;
            kv_part[base + (size_t)d * 80 + nf * 16 + l15] = acc[nf][r];
        }
}

// ---------------- K2b: reduce partials; kv = sum/N, km = col64/N
__global__ __launch_bounds__(256) void k2b_reduce(
    const float* __restrict__ kv_part,
    float* __restrict__ kv, float* __restrict__ km)
{
    int idx = blockIdx.x*256 + threadIdx.x;
    const float inv_n = 1.0f / (float)N_SP;
    if (idx < 16*6*64*64) {
        int bh = idx >> 12, de = idx & 4095;
        int d = de >> 6, e = de & 63;
        float s = 0.f;
        #pragma unroll
        for (int c = 0; c < 7; ++c) s += kv_part[((size_t)(bh*7+c)*64 + d)*80 + e];
        kv[idx] = s * inv_n;
    }
    if (idx < 16*6*64) {
        int bh = idx >> 6, d = idx & 63;
        float s = 0.f;
        #pragma unroll
        for (int c = 0; c < 7; ++c) s += kv_part[((size_t)(bh*7+c)*64 + d)*80 + 64];
        km[idx] = s * inv_n;
    }
}

// ---------------- K3: attn out + fused depthwise 3x3 conv + BN (pe).
// tx -> 4 consecutive pixels, ty -> 4 channels. kv read direct from global (L1/L2).
__global__ __launch_bounds__(256) void k3_attn_pe(
    const float* __restrict__ x, const float* __restrict__ qk,
    const float* __restrict__ kv, const float* __restrict__ km,
    const float* __restrict__ pw,
    const float* __restrict__ pgamma, const float* __restrict__ pbeta,
    const float* __restrict__ pmean, const float* __restrict__ pvar,
    float* __restrict__ out)
{
    __shared__ float qs[64][68];   // [d][n]
    __shared__ float kms[64];
    const int bx = blockIdx.x;    // 49 n tiles
    const int h = blockIdx.y, b = blockIdx.z;
    const int t = threadIdx.x, tx = t & 15, ty = t >> 4;
    const int n0 = bx*64;
    const float* qp  = qk + (size_t)((b*2+0)*384 + h*64)*N_SP;
    const float* kvp = kv + (b*6+h)*4096;
    #pragma unroll
    for (int l = 0; l < 4; ++l) {
        int idx = t + l*256;
        int d = idx >> 4, c = idx & 15;
        *(float4*)&qs[d][c*4] = *(const float4*)&qp[(size_t)d*N_SP + n0 + c*4];
    }
    if (t < 64) kms[t] = km[(b*6+h)*64 + t];
    __syncthreads();

    float acc[4][4] = {};   // [p=pixel][j=channel]
    float den[4] = {};
    #pragma unroll 8
    for (int d = 0; d < 64; ++d) {
        float4 qn = *(const float4*)&qs[d][tx*4];        // 4 pixels (LDS)
        float4 ke = *(const float4*)&kvp[d*64 + ty*4];   // 4 channels (global, L1-hot)
        float qq[4] = {qn.x,qn.y,qn.z,qn.w}, kk[4] = {ke.x,ke.y,ke.z,ke.w};
        float kmd = kms[d];
        #pragma unroll
        for (int p = 0; p < 4; ++p) {
            den[p] += qq[p]*kmd;
            #pragma unroll
            for (int j = 0; j < 4; ++j) acc[p][j] += qq[p]*kk[j];
        }
    }

    // conv: pixels n0+tx*4..+3 lie in one image row (4 | 56)
    const int p0 = n0 + tx*4;
    const int y = p0 / 56, xc = p0 % 56;
    #pragma unroll
    for (int j = 0; j < 4; ++j) {
        int c = h*64 + ty*4 + j;
        const float* xp = x + ((size_t)b*384 + c)*N_SP;
        float s6[3][6];
        #pragma unroll
        for (int dy = 0; dy < 3; ++dy) {
            int yy = y + dy - 1;
            bool yok = (yy >= 0) && (yy < 56);
            float4 mid = make_float4(0.f,0.f,0.f,0.f);
            float lf = 0.f, rt = 0.f;
            if (yok) {
                const float* xr = xp + yy*56;
                mid = *(const float4*)&xr[xc];
                if (xc > 0)  lf = xr[xc-1];
                if (xc < 52) rt = xr[xc+4];
            }
            s6[dy][0]=lf; s6[dy][1]=mid.x; s6[dy][2]=mid.y;
            s6[dy][3]=mid.z; s6[dy][4]=mid.w; s6[dy][5]=rt;
        }
        float w9[9];
        #pragma unroll
        for (int q = 0; q < 9; ++q) w9[q] = pw[c*9 + q];
        float sc2 = pgamma[c] / sqrtf(pvar[c] + BN_EPS);
        float sh2 = pbeta[c] - pmean[c]*sc2;
        float4 r;
        float* pr = (float*)&r;
        #pragma unroll
        for (int p = 0; p < 4; ++p) {
            float conv = 0.f;
            #pragma unroll
            for (int dy = 0; dy < 3; ++dy)
                #pragma unroll
                for (int dx = 0; dx < 3; ++dx)
                    conv += w9[dy*3+dx] * s6[dy][p + dx];
            pr[p] = acc[p][j] / (den[p] + 1e-6f) + (conv*sc2 + sh2);
        }
        *(float4*)&out[((size_t)b*384 + c)*N_SP + p0] = r;
    }
}

extern "C" void kernel_launch(void* const* d_in, const int* in_sizes, int n_in,
                              void* d_out, int out_size, void* d_ws, size_t ws_size,
                              hipStream_t stream)
{
    const float* x        = (const float*)d_in[0];
    const float* qk_w     = (const float*)d_in[1];
    const float* qk_gamma = (const float*)d_in[2];
    const float* qk_beta  = (const float*)d_in[3];
    const float* qk_mean  = (const float*)d_in[4];
    const float* qk_var   = (const float*)d_in[5];
    const float* pe_w     = (const float*)d_in[6];
    const float* pe_gamma = (const float*)d_in[7];
    const float* pe_beta  = (const float*)d_in[8];
    const float* pe_mean  = (const float*)d_in[9];
    const float* pe_var   = (const float*)d_in[10];
    float* out = (float*)d_out;

    float* ws      = (float*)d_ws;
    float* qk      = ws;
    float* kv_part = ws + KVP_OFF;
    float* kv      = ws + KV_OFF;
    float* km      = ws + KM_OFF;
    ushort* whp    = (ushort*)(ws + WH_OFF);
    ushort* wlp    = whp + WSPLIT_N;

    hipLaunchKernelGGL(p0_wsplit, dim3((WSPLIT_N + 255)/256), dim3(256), 0, stream,
                       qk_w, whp, wlp);
    dim3 g1(49, 3, 32);
    hipLaunchKernelGGL(k1_qk_mfma, g1, dim3(256), 0, stream,
                       x, whp, wlp, qk_gamma, qk_beta, qk_mean, qk_var, qk);
    dim3 g2(7, 6, 16);
    hipLaunchKernelGGL(k2_kv_mfma, g2, dim3(256), 0, stream, x, qk, kv_part);
    hipLaunchKernelGGL(k2b_reduce, dim3(1536), dim3(256), 0, stream,
                       kv_part, kv, km);
    dim3 g3(49, 6, 16);
    hipLaunchKernelGGL(k3_attn_pe, g3, dim3(256), 0, stream,
                       x, qk, kv, km, pe_w, pe_gamma, pe_beta, pe_mean, pe_var, out);
}